// Round 4
// baseline (39229.575 us; speedup 1.0000x reference)
//
#include <hip/hip_runtime.h>
#include <math.h>

// BiLSTM-CRF fp32. Round 4: recurrence sync-path restructure.
// - per-wave release flags (no counter RMW, no block barriers at all)
// - per-wave LDS h staging, bank-conflict-free split layout [264]
// - weights register/AGPR-resident as before (4 blocks x 512 thr per (b,dir))
// Sizes: V=30000 E=512 H=256 L=20 NL=2 B=32 T=512.

#define T_SEQ   512
#define BATCH   32
#define HID     256
#define NLAB    20

#define AGENT __HIP_MEMORY_SCOPE_AGENT

// ---------------- prep: permute Wih rows to [unit*4+gate] order, build fused bias ----------------
// Wp[ld][n=j*4+q][k] = Wih[ld][q*256+j][k];  bpp[ld][n] = bias[ld][q*256+j]
__global__ __launch_bounds__(256) void prep_wih_k(const float* __restrict__ Wih,
                                                  const float* __restrict__ bias,
                                                  float* __restrict__ Wp,
                                                  float* __restrict__ bpp) {
  int idx = blockIdx.x * 256 + threadIdx.x;   // over 4*1024*128 float4
  int k4 = idx & 127;
  int n  = (idx >> 7) & 1023;
  int ld = idx >> 17;
  int q = n & 3, j = n >> 2;
  int src = ld * 1024 + q * 256 + j;
  ((float4*)Wp)[idx] = ((const float4*)Wih)[(size_t)src * 128 + k4];
  if (k4 == 0) bpp[ld * 1024 + n] = bias[src];
}

// ---------------- prep: Whh into per-thread register-load order ----------------
// Wreg_f4[ld][bx][i][t] = Whh[ld][q*256+j][kh*128+i*4 .. +3]
//   where t in [0,512): lr=t>>1, kh=t&1; n=bx*256+lr; j=n>>2; q=n&3.
// Strides (float4): ld 65536, bx 16384, i 512, t 1.
__global__ __launch_bounds__(256) void prep_whh_reg_k(const float* __restrict__ Whh,
                                                      float4* __restrict__ Wreg) {
  int idx = blockIdx.x * 256 + threadIdx.x;   // over 4*4*32*512 = 262144 float4
  int t  = idx & 511;
  int i  = (idx >> 9) & 31;
  int bx = (idx >> 14) & 3;
  int ld = idx >> 16;
  int kh = t & 1, lr = t >> 1;
  int n = bx * 256 + lr;
  int j = n >> 2, q = n & 3;
  int kb = kh * 128 + i * 4;
  Wreg[idx] = ((const float4*)Whh)[((size_t)(ld * 1024 + q * 256 + j) * 256 + kb) >> 2];
}

// ---------------- zero the flag words (ws is poisoned; must re-zero every launch) ----------------
__global__ __launch_bounds__(256) void zero_cnt_k(int* __restrict__ p, int n) {
  int i = blockIdx.x * 256 + threadIdx.x;
  if (i < n) p[i] = 0;
}

// ---------------- embedding gather ----------------
__global__ __launch_bounds__(256) void embed_k(const int* __restrict__ inp,
                                               const float* __restrict__ tab,
                                               float* __restrict__ x) {
  int idx = blockIdx.x * 256 + threadIdx.x;   // over 16384*128 float4
  int row = idx >> 7, c = idx & 127;
  int tok = inp[row];
  ((float4*)x)[idx] = ((const float4*)tab)[(size_t)tok * 128 + c];
}

// ---------------- fp32 NT GEMM: C[M][N] = A[M][K] * W[N][K]^T + bias[N] ----------------
#define BM 64
#define BN 64
#define BKK 16
__global__ __launch_bounds__(256) void gemm_nt_k(const float* __restrict__ A,
                                                 const float* __restrict__ W,
                                                 const float* __restrict__ bias,
                                                 float* __restrict__ C,
                                                 int M, int N, int K) {
  __shared__ float As[BKK][BM];
  __shared__ float Ws[BKK][BN];
  int tid = threadIdx.x;
  int bm = blockIdx.x, bn = blockIdx.y;
  int r = tid >> 2, c4 = (tid & 3) * 4;
  int tm = (tid & 15) * 4, tn = (tid >> 4) * 4;
  const float* Ap = A + (size_t)(bm * BM + r) * K + c4;
  const float* Wq = W + (size_t)(bn * BN + r) * K + c4;
  float acc[4][4] = {};
  for (int k0 = 0; k0 < K; k0 += BKK) {
    float4 av = *(const float4*)(Ap + k0);
    float4 wv = *(const float4*)(Wq + k0);
    __syncthreads();
    As[c4 + 0][r] = av.x; As[c4 + 1][r] = av.y; As[c4 + 2][r] = av.z; As[c4 + 3][r] = av.w;
    Ws[c4 + 0][r] = wv.x; Ws[c4 + 1][r] = wv.y; Ws[c4 + 2][r] = wv.z; Ws[c4 + 3][r] = wv.w;
    __syncthreads();
#pragma unroll
    for (int kk = 0; kk < BKK; ++kk) {
      float4 a = *(const float4*)&As[kk][tm];
      float4 b = *(const float4*)&Ws[kk][tn];
      acc[0][0] += a.x * b.x; acc[0][1] += a.x * b.y; acc[0][2] += a.x * b.z; acc[0][3] += a.x * b.w;
      acc[1][0] += a.y * b.x; acc[1][1] += a.y * b.y; acc[1][2] += a.y * b.z; acc[1][3] += a.y * b.w;
      acc[2][0] += a.z * b.x; acc[2][1] += a.z * b.y; acc[2][2] += a.z * b.z; acc[2][3] += a.z * b.w;
      acc[3][0] += a.w * b.x; acc[3][1] += a.w * b.y; acc[3][2] += a.w * b.z; acc[3][3] += a.w * b.w;
    }
  }
  int m0 = bm * BM + tm, n0 = bn * BN + tn;
  float4 bv = *(const float4*)(bias + n0);
  float bb[4] = {bv.x, bv.y, bv.z, bv.w};
#pragma unroll
  for (int i = 0; i < 4; ++i)
#pragma unroll
    for (int jj = 0; jj < 4; ++jj)
      C[(size_t)(m0 + i) * N + n0 + jj] = acc[i][jj] + bb[jj];
}

// ---------------- grouped LSTM recurrence, barrier-free ----------------
// Grid: 256 blocks x 512 threads. Group g=(b,dir): 4 blocks (bx=0..3).
// Block bx owns gate-rows [bx*256,+256) = units [bx*64,+64).
// Thread: lr=tid>>1, kh=tid&1 -> 128 weights in VGPR/AGPR.
// hbuf[g][slot][256]: double-buffered h (relaxed agent atomics).
// flagL[g][32]: per-wave monotone flags; wave wglob publishes s+2 after step s.
// No __syncthreads anywhere: each wave polls flags and stages h into its own
// LDS buffer hw[wv][264] (upper half at +132 -> conflict-free b128 reads).
__global__ __launch_bounds__(512, 2) void lstm_group_k(const float* __restrict__ pre,
                                                       const float4* __restrict__ WregL,
                                                       float* __restrict__ hbuf,
                                                       int* __restrict__ flagL,
                                                       float* __restrict__ Hout) {
  int raw = blockIdx.x;
  // co-XCD heuristic for a group's 4 blocks (perf only; correctness is scope-based)
  int xcd = raw & 7, slot = raw >> 3;
  int g  = xcd * 8 + (slot >> 2);     // 0..63
  int bx = slot & 3;
  int b = g >> 1, d = g & 1;
  int tid = threadIdx.x;
  int ln = tid & 63, wv = tid >> 6;   // lane, wave (0..7)
  int lr = tid >> 1, kh = tid & 1;    // local gate-row, k-half
  int u = bx * 64 + wv * 8 + (ln >> 3);  // unit this octet owns, in [0,256)
  int wglob = bx * 8 + wv;            // 0..31 group-wide wave id

  __shared__ __align__(16) float hw[8][264];

  // --- 128 weights into registers (coalesced float4 loads) ---
  float4 w[32];
  const float4* wp = WregL + ((size_t)(d * 4 + bx) * 32) * 512 + tid;
#pragma unroll
  for (int i = 0; i < 32; ++i) w[i] = wp[i * 512];

  float* hb  = hbuf + g * 512;        // [2][256]
  int*   flg = flagL + g * 32;
  const float* preB = pre + (size_t)b * T_SEQ * 2048 + d * 1024 + bx * 256 + lr;

  float c = 0.f;

  // ---- step 0: h_prev = 0 -> gates are just the input projection ----
  {
    int t = d ? (T_SEQ - 1) : 0;
    float acc = preB[(size_t)t * 2048];
    int base = ln & ~7;
    float gi = __shfl(acc, base + 0, 64);
    float gf = __shfl(acc, base + 2, 64);
    float gg = __shfl(acc, base + 4, 64);
    float go = __shfl(acc, base + 6, 64);
    float iv = 1.f / (1.f + expf(-gi));
    float fv = 1.f / (1.f + expf(-gf));
    float zv = tanhf(gg);
    float ov = 1.f / (1.f + expf(-go));
    c = fv * c + iv * zv;
    float hn = ov * tanhf(c);
    if ((ln & 7) == 0) {
      Hout[(size_t)(b * T_SEQ + t) * 512 + d * HID + u] = hn;
      __hip_atomic_store(&hb[256 + u], hn, __ATOMIC_RELAXED, AGENT);  // slot 1 = h(1)
    }
    if (ln == 0)
      __hip_atomic_store(&flg[wglob], 2, __ATOMIC_RELEASE, AGENT);
  }

  for (int s = 1; s < T_SEQ; ++s) {
    int t = d ? (T_SEQ - 1 - s) : s;
    float pre_v = preB[(size_t)t * 2048];   // issued before the poll -> overlaps

    // ---- wait for h(s): all 32 wave-flags >= s+1 ----
    int target = s + 1;
    for (;;) {
      int f = __hip_atomic_load(&flg[ln & 31], __ATOMIC_RELAXED, AGENT);
      if (__all(f >= target)) break;
      __builtin_amdgcn_s_sleep(1);
    }
    __builtin_amdgcn_fence(__ATOMIC_ACQUIRE, "agent");

    // ---- load h(s) (slot s&1), stage into this wave's LDS buffer ----
    float* hs = hb + (s & 1) * 256;
    float4 hv;
    hv.x = __hip_atomic_load(&hs[4 * ln + 0], __ATOMIC_RELAXED, AGENT);
    hv.y = __hip_atomic_load(&hs[4 * ln + 1], __ATOMIC_RELAXED, AGENT);
    hv.z = __hip_atomic_load(&hs[4 * ln + 2], __ATOMIC_RELAXED, AGENT);
    hv.w = __hip_atomic_load(&hs[4 * ln + 3], __ATOMIC_RELAXED, AGENT);
    int off = (ln < 32) ? 4 * ln : 132 + 4 * (ln - 32);
    *(float4*)&hw[wv][off] = hv;      // wave-internal: ordered by lgkmcnt, no barrier

    // ---- 128 FMAs against register weights ----
    const float* hbase = &hw[wv][kh * 132];
    float a0 = 0.f, a1 = 0.f, a2 = 0.f, a3 = 0.f;
#pragma unroll
    for (int i = 0; i < 32; ++i) {
      float4 h4 = *(const float4*)(hbase + 4 * i);
      a0 = fmaf(w[i].x, h4.x, a0);
      a1 = fmaf(w[i].y, h4.y, a1);
      a2 = fmaf(w[i].z, h4.z, a2);
      a3 = fmaf(w[i].w, h4.w, a3);
    }
    float acc = (a0 + a1) + (a2 + a3);
    acc += __shfl_xor(acc, 1);        // combine k-halves
    acc += pre_v;

    // ---- gate gather + activation (all 8 lanes of the octet, redundant) ----
    int base = ln & ~7;
    float gi = __shfl(acc, base + 0, 64);
    float gf = __shfl(acc, base + 2, 64);
    float gg = __shfl(acc, base + 4, 64);
    float go = __shfl(acc, base + 6, 64);
    float iv = 1.f / (1.f + expf(-gi));
    float fv = 1.f / (1.f + expf(-gf));
    float zv = tanhf(gg);
    float ov = 1.f / (1.f + expf(-go));
    c = fv * c + iv * zv;
    float hn = ov * tanhf(c);

    if ((ln & 7) == 0) {
      Hout[(size_t)(b * T_SEQ + t) * 512 + d * HID + u] = hn;
      if (s < T_SEQ - 1)
        __hip_atomic_store(&hb[((s + 1) & 1) * 256 + u], hn, __ATOMIC_RELAXED, AGENT);
    }
    if (s < T_SEQ - 1 && ln == 0)
      __hip_atomic_store(&flg[wglob], s + 2, __ATOMIC_RELEASE, AGENT);
  }
}

// ---------------- final linear: em[M][20] = H[M][512] * LW[20][512]^T + lb ----------------
__global__ __launch_bounds__(256) void linear20_k(const float* __restrict__ H,
                                                  const float* __restrict__ LW,
                                                  const float* __restrict__ lb,
                                                  float* __restrict__ em) {
  __shared__ float hs[8 * 516];
  __shared__ float lws[20 * 516];
  int tid = threadIdx.x;
  int m0 = blockIdx.x * 8;
  const float4* Hp = (const float4*)(H + (size_t)m0 * 512);
  for (int v = tid; v < 1024; v += 256) {
    int rr = v >> 7, cc = v & 127;
    *(float4*)&hs[rr * 516 + cc * 4] = Hp[v];
  }
  for (int v = tid; v < 2560; v += 256) {
    int ll = v >> 7, cc = v & 127;
    *(float4*)&lws[ll * 516 + cc * 4] = ((const float4*)LW)[v];
  }
  __syncthreads();
  if (tid < 160) {
    int rr = tid / 20, ll = tid % 20;
    float acc = 0.f;
    const float* hp = &hs[rr * 516];
    const float* wp = &lws[ll * 516];
#pragma unroll 8
    for (int k = 0; k < 512; ++k) acc += hp[k] * wp[k];
    em[(size_t)(m0 + rr) * 20 + ll] = acc + lb[ll];
  }
}

// ---------------- Viterbi: one block per sequence ----------------
__global__ __launch_bounds__(640) void viterbi_k(const float* __restrict__ em,
                                                 const float* __restrict__ trans,
                                                 const float* __restrict__ startt,
                                                 const float* __restrict__ endt,
                                                 int* __restrict__ tags) {
  __shared__ float em_s[T_SEQ * NLAB];            // 40 KB
  __shared__ float trans_s[NLAB * NLAB];
  __shared__ float score_s[NLAB];
  __shared__ unsigned char bp[(T_SEQ - 1) * NLAB];
  int b = blockIdx.x, tid = threadIdx.x;
  const float4* emb = (const float4*)(em + (size_t)b * T_SEQ * NLAB);
  for (int v = tid; v < T_SEQ * NLAB / 4; v += 640) ((float4*)em_s)[v] = emb[v];
  for (int v = tid; v < NLAB * NLAB; v += 640) trans_s[v] = trans[v];
  if (tid < NLAB) score_s[tid] = startt[tid] + em[(size_t)b * T_SEQ * NLAB + tid];
  __syncthreads();
  int j = tid >> 5;          // 0..19
  int i = tid & 31;          // prev-label lane
  float tr = (i < NLAB) ? trans_s[i * NLAB + j] : -1e30f;
  for (int t = 1; t < T_SEQ; ++t) {
    float v = (i < NLAB) ? (score_s[i] + tr) : -1e30f;
    int bi = i;
#pragma unroll
    for (int off = 16; off > 0; off >>= 1) {
      float ov = __shfl_down(v, off, 32);
      int oi = __shfl_down(bi, off, 32);
      if (ov > v || (ov == v && oi < bi)) { v = ov; bi = oi; }  // first-max tie-break
    }
    __syncthreads();
    if (i == 0) {
      score_s[j] = v + em_s[t * NLAB + j];
      bp[(t - 1) * NLAB + j] = (unsigned char)bi;
    }
    __syncthreads();
  }
  if (tid == 0) {
    float best = score_s[0] + endt[0]; int cur = 0;
    for (int l = 1; l < NLAB; ++l) {
      float sv = score_s[l] + endt[l];
      if (sv > best) { best = sv; cur = l; }
    }
    int* tb = tags + b * T_SEQ;
    tb[T_SEQ - 1] = cur;
    for (int s2 = T_SEQ - 2; s2 >= 0; --s2) { cur = bp[s2 * NLAB + cur]; tb[s2] = cur; }
  }
}

extern "C" void kernel_launch(void* const* d_in, const int* in_sizes, int n_in,
                              void* d_out, int out_size, void* d_ws, size_t ws_size,
                              hipStream_t stream) {
  const int*   inp   = (const int*)d_in[0];
  // d_in[1] = mask: all True -> identity in the reference; ignored.
  const float* tab   = (const float*)d_in[2];
  const float* Wih   = (const float*)d_in[3];
  const float* Whh   = (const float*)d_in[4];
  const float* bias  = (const float*)d_in[5];
  const float* linW  = (const float*)d_in[6];
  const float* linb  = (const float*)d_in[7];
  const float* trans = (const float*)d_in[8];
  const float* stt   = (const float*)d_in[9];
  const float* endt  = (const float*)d_in[10];
  int* tags = (int*)d_out;

  // workspace layout (floats); ~215.3 MB
  float* ws   = (float*)d_ws;
  float* Wp   = ws;                    // 2,097,152
  float* Wreg = Wp + 2097152;          // 1,048,576 (register-load-ordered Whh)
  float* bpp  = Wreg + 1048576;        // 4,096
  float* x    = bpp + 4096;            // 8,388,608  (embed out / layer-1 output)
  float* H0   = x + 8388608;           // 8,388,608  (layer-0 output)
  float* pre  = H0 + 8388608;          // 33,554,432 (input-proj out, both dirs)
  float* em   = pre + 33554432;        // 327,680
  // hbuf+flags live in the em region (em is written only after all rec kernels)
  float* hbuf = em;                    // 64 groups * 2 slots * 256 = 32,768 floats
  int*   flags = (int*)(em + 32768);   // 2 layers * 64 groups * 32 ints = 4,096 ints

  const float4* WregF4 = (const float4*)Wreg;   // per-ld stride = 65536 float4

  // prep
  hipLaunchKernelGGL(zero_cnt_k, dim3(16), dim3(256), 0, stream, flags, 4096);
  hipLaunchKernelGGL(prep_wih_k, dim3(2048), dim3(256), 0, stream, Wih, bias, Wp, bpp);
  hipLaunchKernelGGL(prep_whh_reg_k, dim3(1024), dim3(256), 0, stream, Whh, (float4*)Wreg);
  // embedding
  hipLaunchKernelGGL(embed_k, dim3(8192), dim3(256), 0, stream, inp, tab, x);

  const int M = BATCH * T_SEQ;   // 16384
  // layer 0 (ld 0,1)
  hipLaunchKernelGGL(gemm_nt_k, dim3(M / BM, 2048 / BN), dim3(256), 0, stream,
                     x, Wp, bpp, pre, M, 2048, 512);
  hipLaunchKernelGGL(lstm_group_k, dim3(256), dim3(512), 0, stream,
                     pre, WregF4, hbuf, flags, H0);
  // layer 1 (ld 2,3 -> WregF4 + 2*65536)
  hipLaunchKernelGGL(gemm_nt_k, dim3(M / BM, 2048 / BN), dim3(256), 0, stream,
                     H0, Wp + 2048 * 512, bpp + 2048, pre, M, 2048, 512);
  hipLaunchKernelGGL(lstm_group_k, dim3(256), dim3(512), 0, stream,
                     pre, WregF4 + 2 * 65536, hbuf, flags + 2048, x);
  // emissions
  hipLaunchKernelGGL(linear20_k, dim3(M / 8), dim3(256), 0, stream, x, linW, linb, em);
  // viterbi decode
  hipLaunchKernelGGL(viterbi_k, dim3(BATCH), dim3(640), 0, stream, em, trans, stt, endt, tags);
}

// Round 5
// 3001.839 us; speedup vs baseline: 13.0685x; 13.0685x over previous
//
#include <hip/hip_runtime.h>
#include <math.h>

// BiLSTM-CRF fp32. Round 5: recurrence h-exchange where the data carries the flag.
// - producer: one 8B relaxed agent atomic store {seq,h} per unit (no RMW/fence/ack)
// - consumer: waves 0-3 poll their own 64 words; __all(seq==s); value rides along
// - Hout staged in 128KB LDS, bulk store after the loop (no vmcnt drain per step)
// - h_s split layout [264] -> conflict-free ds_read_b128 (round-4 win, kept)
// Sizes: V=30000 E=512 H=256 L=20 NL=2 B=32 T=512.

#define T_SEQ   512
#define BATCH   32
#define HID     256
#define NLAB    20

#define AGENT __HIP_MEMORY_SCOPE_AGENT

// ---------------- prep: permute Wih rows to [unit*4+gate] order, build fused bias ----------------
// Wp[ld][n=j*4+q][k] = Wih[ld][q*256+j][k];  bpp[ld][n] = bias[ld][q*256+j]
__global__ __launch_bounds__(256) void prep_wih_k(const float* __restrict__ Wih,
                                                  const float* __restrict__ bias,
                                                  float* __restrict__ Wp,
                                                  float* __restrict__ bpp) {
  int idx = blockIdx.x * 256 + threadIdx.x;   // over 4*1024*128 float4
  int k4 = idx & 127;
  int n  = (idx >> 7) & 1023;
  int ld = idx >> 17;
  int q = n & 3, j = n >> 2;
  int src = ld * 1024 + q * 256 + j;
  ((float4*)Wp)[idx] = ((const float4*)Wih)[(size_t)src * 128 + k4];
  if (k4 == 0) bpp[ld * 1024 + n] = bias[src];
}

// ---------------- prep: Whh into per-thread register-load order ----------------
// Wreg_f4[ld][bx][i][t] = Whh[ld][q*256+j][kh*128+i*4 .. +3]
//   t in [0,512): lr=t>>1, kh=t&1; n=bx*256+lr; j=n>>2; q=n&3.
// Strides (float4): ld 65536, bx 16384, i 512, t 1.
__global__ __launch_bounds__(256) void prep_whh_reg_k(const float* __restrict__ Whh,
                                                      float4* __restrict__ Wreg) {
  int idx = blockIdx.x * 256 + threadIdx.x;   // over 4*4*32*512 = 262144 float4
  int t  = idx & 511;
  int i  = (idx >> 9) & 31;
  int bx = (idx >> 14) & 3;
  int ld = idx >> 16;
  int kh = t & 1, lr = t >> 1;
  int n = bx * 256 + lr;
  int j = n >> 2, q = n & 3;
  int kb = kh * 128 + i * 4;
  Wreg[idx] = ((const float4*)Whh)[((size_t)(ld * 1024 + q * 256 + j) * 256 + kb) >> 2];
}

// ---------------- zero the h-exchange buffer (ws poisoned; graph replays need seq=0) ----------------
__global__ __launch_bounds__(256) void zero_hbuf_k(int4* __restrict__ p) {
  p[blockIdx.x * 256 + threadIdx.x] = int4{0, 0, 0, 0};   // 32768 int4 = 512KB
}

// ---------------- embedding gather ----------------
__global__ __launch_bounds__(256) void embed_k(const int* __restrict__ inp,
                                               const float* __restrict__ tab,
                                               float* __restrict__ x) {
  int idx = blockIdx.x * 256 + threadIdx.x;   // over 16384*128 float4
  int row = idx >> 7, c = idx & 127;
  int tok = inp[row];
  ((float4*)x)[idx] = ((const float4*)tab)[(size_t)tok * 128 + c];
}

// ---------------- fp32 NT GEMM: C[M][N] = A[M][K] * W[N][K]^T + bias[N] ----------------
#define BM 64
#define BN 64
#define BKK 16
__global__ __launch_bounds__(256) void gemm_nt_k(const float* __restrict__ A,
                                                 const float* __restrict__ W,
                                                 const float* __restrict__ bias,
                                                 float* __restrict__ C,
                                                 int M, int N, int K) {
  __shared__ float As[BKK][BM];
  __shared__ float Ws[BKK][BN];
  int tid = threadIdx.x;
  int bm = blockIdx.x, bn = blockIdx.y;
  int r = tid >> 2, c4 = (tid & 3) * 4;
  int tm = (tid & 15) * 4, tn = (tid >> 4) * 4;
  const float* Ap = A + (size_t)(bm * BM + r) * K + c4;
  const float* Wq = W + (size_t)(bn * BN + r) * K + c4;
  float acc[4][4] = {};
  for (int k0 = 0; k0 < K; k0 += BKK) {
    float4 av = *(const float4*)(Ap + k0);
    float4 wv = *(const float4*)(Wq + k0);
    __syncthreads();
    As[c4 + 0][r] = av.x; As[c4 + 1][r] = av.y; As[c4 + 2][r] = av.z; As[c4 + 3][r] = av.w;
    Ws[c4 + 0][r] = wv.x; Ws[c4 + 1][r] = wv.y; Ws[c4 + 2][r] = wv.z; Ws[c4 + 3][r] = wv.w;
    __syncthreads();
#pragma unroll
    for (int kk = 0; kk < BKK; ++kk) {
      float4 a = *(const float4*)&As[kk][tm];
      float4 b = *(const float4*)&Ws[kk][tn];
      acc[0][0] += a.x * b.x; acc[0][1] += a.x * b.y; acc[0][2] += a.x * b.z; acc[0][3] += a.x * b.w;
      acc[1][0] += a.y * b.x; acc[1][1] += a.y * b.y; acc[1][2] += a.y * b.z; acc[1][3] += a.y * b.w;
      acc[2][0] += a.z * b.x; acc[2][1] += a.z * b.y; acc[2][2] += a.z * b.z; acc[2][3] += a.z * b.w;
      acc[3][0] += a.w * b.x; acc[3][1] += a.w * b.y; acc[3][2] += a.w * b.z; acc[3][3] += a.w * b.w;
    }
  }
  int m0 = bm * BM + tm, n0 = bn * BN + tn;
  float4 bv = *(const float4*)(bias + n0);
  float bb[4] = {bv.x, bv.y, bv.z, bv.w};
#pragma unroll
  for (int i = 0; i < 4; ++i)
#pragma unroll
    for (int jj = 0; jj < 4; ++jj)
      C[(size_t)(m0 + i) * N + n0 + jj] = acc[i][jj] + bb[jj];
}

// ---------------- grouped LSTM recurrence, data-as-flag ----------------
// Grid: 256 blocks x 512 threads. Group g=(b,dir): 4 blocks (bx=0..3), raw ids
// differing by 8 (same XCD under round-robin dispatch). Block bx owns gate-rows
// [bx*256,+256) = units [bx*64,+64). Thread: lr=tid>>1, kh=tid&1 -> 128 weight
// floats in registers. hb[g][slot][u]: u64 {seq<<32 | f32bits}, slot = step&1.
// Consumer step s polls slot s&1 for seq==s; the load that satisfies the
// predicate carries the h value. Zero fences, zero RMW, zero per-step global acks.
__global__ __launch_bounds__(512, 2) void lstm_group_k(const float* __restrict__ pre,
                                                       const float4* __restrict__ WregL,
                                                       unsigned long long* __restrict__ hbuf,
                                                       float* __restrict__ Hout) {
  int raw = blockIdx.x;
  int xcd = raw & 7, slot = raw >> 3;
  int g  = xcd * 8 + (slot >> 2);     // 0..63
  int bx = slot & 3;
  int b = g >> 1, d = g & 1;
  int tid = threadIdx.x;
  int lr = tid >> 1, kh = tid & 1;    // local gate-row, k-half

  __shared__ __align__(16) float hout_s[T_SEQ * 64];   // 128 KB: staged H, no per-step HBM ack
  __shared__ __align__(16) float h_s[264];             // split layout: [0..127], pad, [132..259]
  __shared__ __align__(16) float g_s[HID];

  // --- 128 weights into registers (coalesced float4 loads) ---
  float4 w[32];
  const float4* wp = WregL + ((size_t)(d * 4 + bx) * 32) * 512 + tid;
#pragma unroll
  for (int i = 0; i < 32; ++i) w[i] = wp[i * 512];

  unsigned long long* hb = hbuf + g * 512;   // [2][256] u64
  const float* preB = pre + (size_t)b * T_SEQ * 2048 + d * 1024 + bx * 256 + lr;

  float c = 0.f;

  // ---- step 0: h_prev = 0 -> gates = input projection only ----
  {
    int t = d ? (T_SEQ - 1) : 0;
    if ((tid & 1) == 0) g_s[lr] = preB[(size_t)t * 2048];
    __syncthreads();
    if (tid < 64) {
      float4 gg = *(const float4*)&g_s[4 * tid];
      float iv = 1.f / (1.f + expf(-gg.x));
      float fv = 1.f / (1.f + expf(-gg.y));
      float zv = tanhf(gg.z);
      float ov = 1.f / (1.f + expf(-gg.w));
      c = fv * c + iv * zv;
      float hn = ov * tanhf(c);
      hout_s[t * 64 + tid] = hn;
      unsigned long long pv = (1ULL << 32) | (unsigned long long)__float_as_uint(hn);
      __hip_atomic_store(&hb[256 + bx * 64 + tid], pv, __ATOMIC_RELAXED, AGENT);
    }
  }

  for (int s = 1; s < T_SEQ; ++s) {
    int t = d ? (T_SEQ - 1 - s) : s;
    float pre_v = preB[(size_t)t * 2048];    // issued before the poll -> overlaps

    // ---- poll own 64 words of slot s&1; satisfying load carries h ----
    if (tid < 256) {
      unsigned long long* hp = &hb[(s & 1) * 256 + tid];
      unsigned long long v;
      for (;;) {
        v = __hip_atomic_load(hp, __ATOMIC_RELAXED, AGENT);
        if (__all((unsigned)(v >> 32) == (unsigned)s)) break;
      }
      h_s[tid + ((tid >> 7) << 2)] = __uint_as_float((unsigned)v);  // +4 pad for tid>=128
    }
    __syncthreads();                         // C: h_s ready; prior g_s reads done

    // ---- 128 FMAs against register weights (conflict-free split reads) ----
    const float* hbase = &h_s[kh * 132];
    float a0 = 0.f, a1 = 0.f, a2 = 0.f, a3 = 0.f;
#pragma unroll
    for (int i = 0; i < 32; ++i) {
      float4 h4 = *(const float4*)(hbase + 4 * i);
      a0 = fmaf(w[i].x, h4.x, a0);
      a1 = fmaf(w[i].y, h4.y, a1);
      a2 = fmaf(w[i].z, h4.z, a2);
      a3 = fmaf(w[i].w, h4.w, a3);
    }
    float acc = (a0 + a1) + (a2 + a3);
    acc += __shfl_xor(acc, 1);               // combine k-halves (lane pair)

    if ((tid & 1) == 0) g_s[lr] = acc + pre_v;
    __syncthreads();                         // F: g_s ready

    if (tid < 64) {
      float4 gg = *(const float4*)&g_s[4 * tid];
      float iv = 1.f / (1.f + expf(-gg.x));
      float fv = 1.f / (1.f + expf(-gg.y));
      float zv = tanhf(gg.z);
      float ov = 1.f / (1.f + expf(-gg.w));
      c = fv * c + iv * zv;
      float hn = ov * tanhf(c);
      hout_s[t * 64 + tid] = hn;
      if (s < T_SEQ - 1) {
        unsigned long long pv = ((unsigned long long)(unsigned)(s + 1) << 32) |
                                (unsigned long long)__float_as_uint(hn);
        __hip_atomic_store(&hb[((s + 1) & 1) * 256 + bx * 64 + tid], pv,
                           __ATOMIC_RELAXED, AGENT);
      }
    }
  }

  // ---- bulk write staged H to global (coalesced float4) ----
  __syncthreads();
  const float4* src = (const float4*)hout_s;
  float4* dst = (float4*)Hout;
#pragma unroll
  for (int i = 0; i < 16; ++i) {
    int idx = i * 512 + tid;                 // 0..8191 float4
    int t = idx >> 4, c4 = idx & 15;
    dst[((size_t)(b * T_SEQ + t) << 7) + d * 64 + bx * 16 + c4] = src[idx];
  }
}

// ---------------- final linear: em[M][20] = H[M][512] * LW[20][512]^T + lb ----------------
__global__ __launch_bounds__(256) void linear20_k(const float* __restrict__ H,
                                                  const float* __restrict__ LW,
                                                  const float* __restrict__ lb,
                                                  float* __restrict__ em) {
  __shared__ float hs[8 * 516];
  __shared__ float lws[20 * 516];
  int tid = threadIdx.x;
  int m0 = blockIdx.x * 8;
  const float4* Hp = (const float4*)(H + (size_t)m0 * 512);
  for (int v = tid; v < 1024; v += 256) {
    int rr = v >> 7, cc = v & 127;
    *(float4*)&hs[rr * 516 + cc * 4] = Hp[v];
  }
  for (int v = tid; v < 2560; v += 256) {
    int ll = v >> 7, cc = v & 127;
    *(float4*)&lws[ll * 516 + cc * 4] = ((const float4*)LW)[v];
  }
  __syncthreads();
  if (tid < 160) {
    int rr = tid / 20, ll = tid % 20;
    float acc = 0.f;
    const float* hp = &hs[rr * 516];
    const float* wp = &lws[ll * 516];
#pragma unroll 8
    for (int k = 0; k < 512; ++k) acc += hp[k] * wp[k];
    em[(size_t)(m0 + rr) * 20 + ll] = acc + lb[ll];
  }
}

// ---------------- Viterbi: one block per sequence ----------------
__global__ __launch_bounds__(640) void viterbi_k(const float* __restrict__ em,
                                                 const float* __restrict__ trans,
                                                 const float* __restrict__ startt,
                                                 const float* __restrict__ endt,
                                                 int* __restrict__ tags) {
  __shared__ float em_s[T_SEQ * NLAB];            // 40 KB
  __shared__ float trans_s[NLAB * NLAB];
  __shared__ float score_s[NLAB];
  __shared__ unsigned char bp[(T_SEQ - 1) * NLAB];
  int b = blockIdx.x, tid = threadIdx.x;
  const float4* emb = (const float4*)(em + (size_t)b * T_SEQ * NLAB);
  for (int v = tid; v < T_SEQ * NLAB / 4; v += 640) ((float4*)em_s)[v] = emb[v];
  for (int v = tid; v < NLAB * NLAB; v += 640) trans_s[v] = trans[v];
  if (tid < NLAB) score_s[tid] = startt[tid] + em[(size_t)b * T_SEQ * NLAB + tid];
  __syncthreads();
  int j = tid >> 5;          // 0..19
  int i = tid & 31;          // prev-label lane
  float tr = (i < NLAB) ? trans_s[i * NLAB + j] : -1e30f;
  for (int t = 1; t < T_SEQ; ++t) {
    float v = (i < NLAB) ? (score_s[i] + tr) : -1e30f;
    int bi = i;
#pragma unroll
    for (int off = 16; off > 0; off >>= 1) {
      float ov = __shfl_down(v, off, 32);
      int oi = __shfl_down(bi, off, 32);
      if (ov > v || (ov == v && oi < bi)) { v = ov; bi = oi; }  // first-max tie-break
    }
    __syncthreads();
    if (i == 0) {
      score_s[j] = v + em_s[t * NLAB + j];
      bp[(t - 1) * NLAB + j] = (unsigned char)bi;
    }
    __syncthreads();
  }
  if (tid == 0) {
    float best = score_s[0] + endt[0]; int cur = 0;
    for (int l = 1; l < NLAB; ++l) {
      float sv = score_s[l] + endt[l];
      if (sv > best) { best = sv; cur = l; }
    }
    int* tb = tags + b * T_SEQ;
    tb[T_SEQ - 1] = cur;
    for (int s2 = T_SEQ - 2; s2 >= 0; --s2) { cur = bp[s2 * NLAB + cur]; tb[s2] = cur; }
  }
}

extern "C" void kernel_launch(void* const* d_in, const int* in_sizes, int n_in,
                              void* d_out, int out_size, void* d_ws, size_t ws_size,
                              hipStream_t stream) {
  const int*   inp   = (const int*)d_in[0];
  // d_in[1] = mask: all True -> identity in the reference; ignored.
  const float* tab   = (const float*)d_in[2];
  const float* Wih   = (const float*)d_in[3];
  const float* Whh   = (const float*)d_in[4];
  const float* bias  = (const float*)d_in[5];
  const float* linW  = (const float*)d_in[6];
  const float* linb  = (const float*)d_in[7];
  const float* trans = (const float*)d_in[8];
  const float* stt   = (const float*)d_in[9];
  const float* endt  = (const float*)d_in[10];
  int* tags = (int*)d_out;

  // workspace layout (floats); ~215.3 MB total, same extents as rounds 1-4
  float* ws   = (float*)d_ws;
  float* Wp   = ws;                    // 2,097,152
  float* Wreg = Wp + 2097152;          // 1,048,576 (register-load-ordered Whh)
  float* bpp  = Wreg + 1048576;        // 4,096
  float* x    = bpp + 4096;            // 8,388,608  (embed out / layer-1 output)
  float* H0   = x + 8388608;           // 8,388,608  (layer-0 output)
  float* pre  = H0 + 8388608;          // 33,554,432 (input-proj out, both dirs)
  float* em   = pre + 33554432;        // 327,680
  // h-exchange lives in the em region (em written only after all rec kernels):
  // 2 layers * 64 groups * 512 u64 = 65536 u64 = 131072 floats < 327680 ok
  unsigned long long* hbuf = (unsigned long long*)em;

  const float4* WregF4 = (const float4*)Wreg;   // per-ld stride = 65536 float4

  // prep
  hipLaunchKernelGGL(zero_hbuf_k, dim3(128), dim3(256), 0, stream, (int4*)hbuf);
  hipLaunchKernelGGL(prep_wih_k, dim3(2048), dim3(256), 0, stream, Wih, bias, Wp, bpp);
  hipLaunchKernelGGL(prep_whh_reg_k, dim3(1024), dim3(256), 0, stream, Whh, (float4*)Wreg);
  // embedding
  hipLaunchKernelGGL(embed_k, dim3(8192), dim3(256), 0, stream, inp, tab, x);

  const int M = BATCH * T_SEQ;   // 16384
  // layer 0 (ld 0,1)
  hipLaunchKernelGGL(gemm_nt_k, dim3(M / BM, 2048 / BN), dim3(256), 0, stream,
                     x, Wp, bpp, pre, M, 2048, 512);
  hipLaunchKernelGGL(lstm_group_k, dim3(256), dim3(512), 0, stream,
                     pre, WregF4, hbuf, H0);
  // layer 1 (ld 2,3 -> WregF4 + 2*65536; hbuf + 64*512)
  hipLaunchKernelGGL(gemm_nt_k, dim3(M / BM, 2048 / BN), dim3(256), 0, stream,
                     H0, Wp + 2048 * 512, bpp + 2048, pre, M, 2048, 512);
  hipLaunchKernelGGL(lstm_group_k, dim3(256), dim3(512), 0, stream,
                     pre, WregF4 + 2 * 65536, hbuf + 32768, x);
  // emissions
  hipLaunchKernelGGL(linear20_k, dim3(M / 8), dim3(256), 0, stream, x, linW, linb, em);
  // viterbi decode
  hipLaunchKernelGGL(viterbi_k, dim3(BATCH), dim3(640), 0, stream, em, trans, stt, endt, tags);
}